// Round 2
// baseline (279.978 us; speedup 1.0000x reference)
//
#include <hip/hip_runtime.h>
#include <hip/hip_bf16.h>

// Welford over batch dim: x [B=64, C=256, H=56, W=56] fp32 -> out [2, C, H, W]
// out[0,:] = running mean m, out[1,:] = M2 accumulator s (var = s/(n-1)).
// One thread per 4 contiguous feature positions (float4); exact sequential
// recurrence over B=64 samples in registers, matching the reference op order:
//   n += 1; d = xi - m; m += d / n; s += d * (xi - m)

#define B_SAMPLES 64

__global__ __launch_bounds__(256) void welford_kernel(
    const float4* __restrict__ x, float4* __restrict__ out, int chw4) {
  // grid-stride for robustness; with grid=784 each thread runs exactly once
  for (int idx = blockIdx.x * blockDim.x + threadIdx.x; idx < chw4;
       idx += gridDim.x * blockDim.x) {
    float4 m = make_float4(0.f, 0.f, 0.f, 0.f);
    float4 s = make_float4(0.f, 0.f, 0.f, 0.f);

    const float4* p = x + idx;

#pragma unroll 8
    for (int b = 0; b < B_SAMPLES; ++b) {
      float4 xi = p[(size_t)b * (size_t)chw4];
      float n = (float)(b + 1);

      float d;
      d = xi.x - m.x; m.x += d / n; s.x += d * (xi.x - m.x);
      d = xi.y - m.y; m.y += d / n; s.y += d * (xi.y - m.y);
      d = xi.z - m.z; m.z += d / n; s.z += d * (xi.z - m.z);
      d = xi.w - m.w; m.w += d / n; s.w += d * (xi.w - m.w);
    }

    out[idx] = m;          // mean -> out[0, chw]
    out[idx + chw4] = s;   // M2   -> out[1, chw]
  }
}

extern "C" void kernel_launch(void* const* d_in, const int* in_sizes, int n_in,
                              void* d_out, int out_size, void* d_ws, size_t ws_size,
                              hipStream_t stream) {
  const float* x = (const float*)d_in[0];
  float* out = (float*)d_out;

  const int total = in_sizes[0];        // B * C * H * W = 51380224
  const int chw = total / B_SAMPLES;    // 802816
  const int chw4 = chw / 4;             // 200704

  const int block = 256;
  const int grid = (chw4 + block - 1) / block;  // 784
  welford_kernel<<<grid, block, 0, stream>>>(
      (const float4*)x, (float4*)out, chw4);
}

// Round 4
// 277.936 us; speedup vs baseline: 1.0073x; 1.0073x over previous
//
#include <hip/hip_runtime.h>
#include <hip/hip_bf16.h>

// Welford over batch dim: x [B=64, C=256, H=56, W=56] fp32 -> out [2, C, H, W]
// out[0,:] = running mean m, out[1,:] = M2 accumulator s (var = s/(n-1)).
// One thread per 2 contiguous feature positions (float2): 401408 threads =
// 1568 blocks = ~24.5 waves/CU for latency hiding (vs 12 at float4 granularity).
// Exact sequential recurrence over B=64 samples, matching reference op order:
//   n += 1; d = xi - m; m += d / n; s += d * (xi - m)   (bit-exact, absmax 0)

#define B_SAMPLES 64

__global__ __launch_bounds__(256) void welford_kernel(
    const float2* __restrict__ x, float2* __restrict__ out, int chw2) {
  int idx = blockIdx.x * blockDim.x + threadIdx.x;
  if (idx >= chw2) return;

  float2 m = make_float2(0.f, 0.f);
  float2 s = make_float2(0.f, 0.f);

  const float2* p = x + idx;

#pragma unroll 16
  for (int b = 0; b < B_SAMPLES; ++b) {
    float2 xi = p[(size_t)b * (size_t)chw2];
    float n = (float)(b + 1);

    float d;
    d = xi.x - m.x; m.x += d / n; s.x += d * (xi.x - m.x);
    d = xi.y - m.y; m.y += d / n; s.y += d * (xi.y - m.y);
  }

  out[idx] = m;          // mean -> out[0, chw]
  out[idx + chw2] = s;   // M2   -> out[1, chw]
}

extern "C" void kernel_launch(void* const* d_in, const int* in_sizes, int n_in,
                              void* d_out, int out_size, void* d_ws, size_t ws_size,
                              hipStream_t stream) {
  const float* x = (const float*)d_in[0];
  float* out = (float*)d_out;

  const int total = in_sizes[0];        // B * C * H * W = 51380224
  const int chw = total / B_SAMPLES;    // 802816
  const int chw2 = chw / 2;             // 401408

  const int block = 256;
  const int grid = (chw2 + block - 1) / block;  // 1568
  welford_kernel<<<grid, block, 0, stream>>>(
      (const float2*)x, (float2*)out, chw2);
}